// Round 1
// baseline (115.373 us; speedup 1.0000x reference)
//
#include <hip/hip_runtime.h>

// Problem constants (fixed by reference setup_inputs):
//   M=2, L=6, N=512, d=2, H=64;  V_K=1.0, SIGMA=0.1, EPS=1e-10
#define MM 2
#define LL 6
#define NN 512
#define HH 64
#define K_TAB 512
#define RMAX 16.0f
#define H_STEP (RMAX / (float)K_TAB)   // 0.03125
#define HINV   ((float)K_TAB / RMAX)   // 32.0
#define NBLK (MM * LL * (NN / 4))      // 1536 pair blocks

// ws layout:
//   0    : float2 nodes[K_TAB+1]  (4104 B)
//   8192 : double acc[48]         (384 B)   per-(m,l) {sum phi, sum d2phi, sum drift^2, sum |x|^2}
//   8576 : unsigned cnt           (ticket counter)
// acc/cnt are re-zeroed by build_nodes every iteration (ws is re-poisoned by
// the harness between iterations). Kernel-boundary ordering makes the zeros
// visible to pair_finalize.

__device__ __forceinline__ float wave_reduce_sum(float v) {
    #pragma unroll
    for (int m = 32; m > 0; m >>= 1) v += __shfl_xor(v, m, 64);
    return v;
}

// One wave per table node; lane indexes hidden unit h (and output unit k).
__global__ __launch_bounds__(256) void build_nodes(
        const float* __restrict__ w1, const float* __restrict__ b1,
        const float* __restrict__ W2, const float* __restrict__ b2,
        const float* __restrict__ w3, const float* __restrict__ b3,
        float2* __restrict__ nodes, double* __restrict__ acc,
        unsigned* __restrict__ cnt) {
    // zero the fp64 accumulators + ticket for this iteration (ws is poisoned)
    if (blockIdx.x == 0) {
        if (threadIdx.x < 48) acc[threadIdx.x] = 0.0;
        if (threadIdx.x == 48) *cnt = 0u;
    }

    int gid  = blockIdx.x * blockDim.x + threadIdx.x;
    int node = gid >> 6;
    int lane = gid & 63;
    if (node > K_TAB) return;        // K_TAB+1 nodes

    float r = (float)node * H_STEP;

    // layer 1 (elementwise in h = lane)
    float w1l = w1[lane];
    float u   = fmaf(r, w1l, b1[lane]);
    float t1  = tanhf(u);
    float e1  = 1.0f - t1 * t1;
    float h1  = t1;
    float h1p = e1 * w1l;            // d h1 / dr

    // layer 2 matvec: v_k = sum_h h1_h * W2[h,k] + b2_k   (k = lane)
    float v = b2[lane], vp = 0.0f;
    #pragma unroll
    for (int h = 0; h < HH; ++h) {
        float a  = __shfl(h1,  h, 64);
        float ap = __shfl(h1p, h, 64);
        float w  = W2[h * HH + lane];
        v  = fmaf(a,  w, v);
        vp = fmaf(ap, w, vp);
    }
    float t2 = tanhf(v);
    float e2 = 1.0f - t2 * t2;
    float w3l = w3[lane];
    float sphi = wave_reduce_sum(w3l * t2);
    float sdp  = wave_reduce_sum(w3l * e2 * vp);
    if (lane == 0)
        nodes[node] = make_float2(sphi + b3[0], sdp * H_STEP);
}

// One wave per particle i; lanes split j. 4 waves (4 i's) per block.
// Block-private cubic-Hermite coeff table in LDS. Each block folds its 4
// stats into per-(m,l) fp64 accumulators via agent-scope atomics, takes a
// ticket; the last block does the final fp64 combine (no separate kernel).
__global__ __launch_bounds__(256) void pair_finalize(
        const float* __restrict__ data, const float2* __restrict__ nodes,
        double* __restrict__ acc, unsigned* __restrict__ cnt,
        const float* __restrict__ ts, float* __restrict__ out) {
    const int blocks_per_ml = NN / 4;
    int ml = blockIdx.x / blocks_per_ml;
    int i4 = blockIdx.x % blocks_per_ml;

    __shared__ float4 coef[K_TAB];   // 8 KB
    __shared__ float2 xs[NN];        // 4 KB
    __shared__ float  red[4 * 4];

    // build cubic-Hermite coeffs from node table (L2-broadcast reads)
    #pragma unroll
    for (int it = 0; it < K_TAB / 256; ++it) {
        int e = it * 256 + threadIdx.x;
        float2 g0 = nodes[e];
        float2 g1 = nodes[e + 1];
        float  d  = g1.x - g0.x;
        coef[e] = make_float4(g0.x, g0.y,
                              3.0f * d - 2.0f * g0.y - g1.y,
                              g0.y + g1.y - 2.0f * d);
    }
    // stage the 512 points of this (m,l): 1024 floats = 256 float4
    {
        const float4* src = (const float4*)(data + (size_t)ml * NN * 2);
        ((float4*)xs)[threadIdx.x] = src[threadIdx.x];
    }
    __syncthreads();

    int wv   = threadIdx.x >> 6;
    int lane = threadIdx.x & 63;
    int i    = i4 * 4 + wv;
    float2 xi = xs[i];

    float aphi = 0.0f, ad2 = 0.0f, agx = 0.0f, agy = 0.0f;
    #pragma unroll
    for (int jj = 0; jj < NN / 64; ++jj) {
        int j = jj * 64 + lane;
        float2 xj = xs[j];
        float dx = xi.x - xj.x;
        float dy = xi.y - xj.y;
        float ssq = fmaf(dx, dx, dy * dy);
        // one v_rsq instead of sqrt + rcp:
        //   ir = 1/max(r,1e-10); rr = r (exactly 0 when ssq==0)
        float ir  = __builtin_amdgcn_rsqf(fmaxf(ssq, 1e-20f));
        float rr  = ssq * ir;
        float f   = rr * HINV;
        int   idx = (int)f;
        idx = idx > (K_TAB - 1) ? (K_TAB - 1) : idx;
        float tt = f - (float)idx;
        float4 c = coef[idx];
        // phi   = c0 + t(c1 + t(c2 + t c3))
        // dphi  = (c1 + t(2c2 + 3c3 t)) / h
        // d2phi = (2c2 + 6c3 t) / h^2
        float phi  = fmaf(tt, fmaf(tt, fmaf(tt, c.w, c.z), c.y), c.x);
        float dph  = fmaf(tt, fmaf(tt, 3.0f * c.w, 2.0f * c.z), c.y) * HINV;
        float d2ph = fmaf(tt, 6.0f * c.w, 2.0f * c.z) * (HINV * HINV);
        bool off = (j != i);
        aphi += off ? phi  : 0.0f;
        ad2  += off ? d2ph : 0.0f;
        // dx=dy=0 when j==i -> gradient terms self-mask
        float s = dph * ir;
        agx = fmaf(s, dx, agx);
        agy = fmaf(s, dy, agy);
    }

    aphi = wave_reduce_sum(aphi);
    ad2  = wave_reduce_sum(ad2);
    agx  = wave_reduce_sum(agx);
    agy  = wave_reduce_sum(agy);

    if (lane == 0) {
        const float invN = 1.0f / (float)NN;
        float driftx = -xi.x - agx * invN;   // V_K = 1
        float drifty = -xi.y - agy * invN;
        float dr2 = fmaf(driftx, driftx, drifty * drifty);
        float vsq = fmaf(xi.x, xi.x, xi.y * xi.y);
        red[wv * 4 + 0] = aphi;
        red[wv * 4 + 1] = ad2;
        red[wv * 4 + 2] = dr2;
        red[wv * 4 + 3] = vsq;
    }
    __syncthreads();

    if (threadIdx.x == 0) {
        // combine this block's 4 waves, fold into fp64 per-(m,l) accumulators.
        // All four adds are in thread-0 program order before the acq_rel
        // ticket RMW -> release sequence on cnt makes them visible to the
        // winning block's acquire.
        float s0 = red[0] + red[4] + red[8]  + red[12];
        float s1 = red[1] + red[5] + red[9]  + red[13];
        float s2 = red[2] + red[6] + red[10] + red[14];
        float s3 = red[3] + red[7] + red[11] + red[15];
        __hip_atomic_fetch_add(&acc[ml * 4 + 0], (double)s0,
                               __ATOMIC_RELAXED, __HIP_MEMORY_SCOPE_AGENT);
        __hip_atomic_fetch_add(&acc[ml * 4 + 1], (double)s1,
                               __ATOMIC_RELAXED, __HIP_MEMORY_SCOPE_AGENT);
        __hip_atomic_fetch_add(&acc[ml * 4 + 2], (double)s2,
                               __ATOMIC_RELAXED, __HIP_MEMORY_SCOPE_AGENT);
        __hip_atomic_fetch_add(&acc[ml * 4 + 3], (double)s3,
                               __ATOMIC_RELAXED, __HIP_MEMORY_SCOPE_AGENT);
        unsigned ticket = __hip_atomic_fetch_add(cnt, 1u,
                               __ATOMIC_ACQ_REL, __HIP_MEMORY_SCOPE_AGENT);
        if (ticket == NBLK - 1) {
            // last block: final fp64 combine (same math as old finalize)
            double s[48];
            #pragma unroll
            for (int k = 0; k < 48; ++k)
                s[k] = __hip_atomic_load(&acc[k],
                           __ATOMIC_RELAXED, __HIP_MEMORY_SCOPE_AGENT);
            const double N = (double)NN;
            const double SIG2 = 0.01;   // SIGMA^2
            const double VKD  = 2.0;    // V_K * d
            double diss = 0.0, diffu = 0.0, dE = 0.0;
            #pragma unroll
            for (int m = 0; m < MM; ++m) {
                double E0 = 0.0;
                #pragma unroll
                for (int l = 0; l < LL; ++l) {
                    int idx = m * LL + l;
                    double sphi = s[idx * 4 + 0];
                    double sd2  = s[idx * 4 + 1];
                    double sdr  = s[idx * 4 + 2];
                    double sv   = s[idx * 4 + 3];
                    double E = 0.5 * sv / N + sphi / (N * N);
                    if (l == 0) E0 = E;
                    if (l == LL - 1) dE += E - E0;
                    if (l < LL - 1) {
                        double dt = (double)ts[l + 1] - (double)ts[l];
                        diss  += sdr / N * dt;
                        diffu += SIG2 * (VKD + sd2 / (N * N)) * dt;
                    }
                }
            }
            double res = (diss + diffu - 2.0 * dE) / (double)(MM * (LL - 1));
            out[0] = (float)(res * res);
        }
    }
}

extern "C" void kernel_launch(void* const* d_in, const int* in_sizes, int n_in,
                              void* d_out, int out_size, void* d_ws, size_t ws_size,
                              hipStream_t stream) {
    const float* data = (const float*)d_in[0];
    const float* t    = (const float*)d_in[1];
    const float* w1   = (const float*)d_in[2];
    const float* b1   = (const float*)d_in[3];
    const float* W2   = (const float*)d_in[4];
    const float* b2   = (const float*)d_in[5];
    const float* w3   = (const float*)d_in[6];
    const float* b3   = (const float*)d_in[7];

    float2*   nodes = (float2*)d_ws;
    double*   acc   = (double*)((char*)d_ws + 8192);
    unsigned* cnt   = (unsigned*)((char*)d_ws + 8576);

    // K_TAB+1 = 513 nodes, one wave each -> 129 blocks of 4 waves
    build_nodes<<<129, 256, 0, stream>>>(w1, b1, W2, b2, w3, b3, nodes, acc, cnt);
    // 12 (m,l) * 128 blocks = 1536; fused reduction + last-block finalize
    pair_finalize<<<NBLK, 256, 0, stream>>>(data, nodes, acc, cnt, t, (float*)d_out);
}

// Round 2
// 79.916 us; speedup vs baseline: 1.4437x; 1.4437x over previous
//
#include <hip/hip_runtime.h>

// Problem constants (fixed by reference setup_inputs):
//   M=2, L=6, N=512, d=2, H=64;  V_K=1.0, SIGMA=0.1, EPS=1e-10
#define MM 2
#define LL 6
#define NN 512
#define HH 64
#define K_TAB 512
#define RMAX 16.0f
#define H_STEP (RMAX / (float)K_TAB)   // 0.03125
#define HINV   ((float)K_TAB / RMAX)   // 32.0
#define BPML 32                        // pair blocks per (m,l)
#define NPBLK (MM * LL * BPML)         // 384 pair blocks
#define IPB (NN / BPML)                // 16 particles per block
#define IPW 4                          // 4 particles per wave

// ws layout:
//   0    : float4 coef[K_TAB]   (8192 B)  cubic-Hermite coeffs, built by build_nodes
//   8192 : float4 partial[NPBLK] (6144 B) per-block {sum phi, sum d2phi, sum drift^2, sum |x|^2}
// All ws bytes used are fully rewritten every iteration (poison-safe).
// Ordering between kernels comes from stream dispatch boundaries — NO device
// fences/atomics (round-1 lesson: per-block agent-scope acq_rel = buffer_wbl2/
// buffer_inv per block on non-coherent per-XCD L2s = catastrophic).

__device__ __forceinline__ float wave_reduce_sum(float v) {
    #pragma unroll
    for (int m = 32; m > 0; m >>= 1) v += __shfl_xor(v, m, 64);
    return v;
}

// One wave per table interval e in [0,512): evaluates the MLP (value + dr
// derivative via forward-mode) at r_e AND r_{e+1}, sharing the W2 loads, and
// emits the cubic-Hermite coefficient float4 directly.
__global__ __launch_bounds__(256) void build_nodes(
        const float* __restrict__ w1, const float* __restrict__ b1,
        const float* __restrict__ W2, const float* __restrict__ b2,
        const float* __restrict__ w3, const float* __restrict__ b3,
        float4* __restrict__ coefg) {
    int gid  = blockIdx.x * blockDim.x + threadIdx.x;
    int e    = gid >> 6;             // 512 waves exactly (128 blocks * 4)
    int lane = gid & 63;

    float r0 = (float)e * H_STEP;
    float r1 = r0 + H_STEP;

    // layer 1 (elementwise in h = lane), both r's
    float w1l = w1[lane];
    float b1l = b1[lane];
    float t10 = tanhf(fmaf(r0, w1l, b1l));
    float t11 = tanhf(fmaf(r1, w1l, b1l));
    float p10 = (1.0f - t10 * t10) * w1l;   // d h1 / dr at r0
    float p11 = (1.0f - t11 * t11) * w1l;

    // layer 2 matvec for both r's on shared W2 loads
    float b2l = b2[lane];
    float v0 = b2l, vp0 = 0.0f, v1 = b2l, vp1 = 0.0f;
    #pragma unroll
    for (int h = 0; h < HH; ++h) {
        float a0 = __shfl(t10, h, 64);
        float q0 = __shfl(p10, h, 64);
        float a1 = __shfl(t11, h, 64);
        float q1 = __shfl(p11, h, 64);
        float w  = W2[h * HH + lane];
        v0  = fmaf(a0, w, v0);
        vp0 = fmaf(q0, w, vp0);
        v1  = fmaf(a1, w, v1);
        vp1 = fmaf(q1, w, vp1);
    }
    float t20 = tanhf(v0);
    float t21 = tanhf(v1);
    float w3l = w3[lane];
    float sphi0 = wave_reduce_sum(w3l * t20);
    float sdp0  = wave_reduce_sum(w3l * (1.0f - t20 * t20) * vp0);
    float sphi1 = wave_reduce_sum(w3l * t21);
    float sdp1  = wave_reduce_sum(w3l * (1.0f - t21 * t21) * vp1);
    if (lane == 0) {
        float phi0 = sphi0 + b3[0];
        float phi1 = sphi1 + b3[0];
        float m0 = sdp0 * H_STEP;        // derivative scaled to t-units
        float m1 = sdp1 * H_STEP;
        float d  = phi1 - phi0;
        coefg[e] = make_float4(phi0, m0,
                               3.0f * d - 2.0f * m0 - m1,
                               m0 + m1 - 2.0f * d);
    }
}

// 384 blocks: 12 (m,l) * 32. Each block owns 16 particles; each wave owns 4,
// so every LDS xj read feeds 4 interpolations. Per-block private partial slot
// (plain store, no atomics).
__global__ __launch_bounds__(256) void pair_kernel(
        const float* __restrict__ data, const float4* __restrict__ coefg,
        float4* __restrict__ partial) {
    int ml = blockIdx.x >> 5;        // / BPML
    int ig = blockIdx.x & (BPML - 1);

    __shared__ float4 coef[K_TAB];   // 8 KB
    __shared__ float2 xs[NN];        // 4 KB
    __shared__ float  red[4 * 4];

    // stage coef table (8 KB) and this (m,l)'s 512 points (4 KB)
    #pragma unroll
    for (int it = 0; it < K_TAB / 256; ++it)
        coef[it * 256 + threadIdx.x] = coefg[it * 256 + threadIdx.x];
    {
        const float4* src = (const float4*)(data + (size_t)ml * NN * 2);
        ((float4*)xs)[threadIdx.x] = src[threadIdx.x];
    }
    __syncthreads();

    int wv   = threadIdx.x >> 6;
    int lane = threadIdx.x & 63;
    int ibase = ig * IPB + wv * IPW;

    float2 xi[IPW];
    #pragma unroll
    for (int q = 0; q < IPW; ++q) xi[q] = xs[ibase + q];

    float aphi[IPW], ad2[IPW], agx[IPW], agy[IPW];
    #pragma unroll
    for (int q = 0; q < IPW; ++q) { aphi[q] = 0.f; ad2[q] = 0.f; agx[q] = 0.f; agy[q] = 0.f; }

    #pragma unroll
    for (int jj = 0; jj < NN / 64; ++jj) {
        int j = jj * 64 + lane;
        float2 xj = xs[j];
        #pragma unroll
        for (int q = 0; q < IPW; ++q) {
            float dx = xi[q].x - xj.x;
            float dy = xi[q].y - xj.y;
            float ssq = fmaf(dx, dx, dy * dy);
            float ir  = __builtin_amdgcn_rsqf(fmaxf(ssq, 1e-20f));
            float rr  = ssq * ir;                 // exactly 0 when ssq==0
            float f   = rr * HINV;
            int   idx = (int)f;
            idx = idx > (K_TAB - 1) ? (K_TAB - 1) : idx;
            float tt = f - (float)idx;
            float4 c = coef[idx];
            // phi   = c0 + t(c1 + t(c2 + t c3))
            // dphi  = (c1 + t(2c2 + 3c3 t)) / h
            // d2phi = (2c2 + 6c3 t) / h^2
            float phi  = fmaf(tt, fmaf(tt, fmaf(tt, c.w, c.z), c.y), c.x);
            float dph  = fmaf(tt, fmaf(tt, 3.0f * c.w, 2.0f * c.z), c.y) * HINV;
            float d2ph = fmaf(tt, 6.0f * c.w, 2.0f * c.z) * (HINV * HINV);
            bool off = (j != ibase + q);
            aphi[q] += off ? phi  : 0.0f;
            ad2[q]  += off ? d2ph : 0.0f;
            // dx=dy=0 when j==i -> gradient terms self-mask
            float s = dph * ir;
            agx[q] = fmaf(s, dx, agx[q]);
            agy[q] = fmaf(s, dy, agy[q]);
        }
    }

    // reduce each particle's 4 stats across the wave; lane 0 accumulates the
    // wave's 4 particles into 4 scalars
    float s0 = 0.f, s1 = 0.f, s2 = 0.f, s3 = 0.f;
    #pragma unroll
    for (int q = 0; q < IPW; ++q) {
        float a  = wave_reduce_sum(aphi[q]);
        float d2 = wave_reduce_sum(ad2[q]);
        float gx = wave_reduce_sum(agx[q]);
        float gy = wave_reduce_sum(agy[q]);
        if (lane == 0) {
            const float invN = 1.0f / (float)NN;
            float driftx = -xi[q].x - gx * invN;   // V_K = 1
            float drifty = -xi[q].y - gy * invN;
            s0 += a;
            s1 += d2;
            s2 += fmaf(driftx, driftx, drifty * drifty);
            s3 += fmaf(xi[q].x, xi[q].x, xi[q].y * xi[q].y);
        }
    }
    if (lane == 0) {
        red[wv * 4 + 0] = s0;
        red[wv * 4 + 1] = s1;
        red[wv * 4 + 2] = s2;
        red[wv * 4 + 3] = s3;
    }
    __syncthreads();
    if (threadIdx.x == 0) {
        partial[blockIdx.x] = make_float4(
            red[0] + red[4] + red[8]  + red[12],
            red[1] + red[5] + red[9]  + red[13],
            red[2] + red[6] + red[10] + red[14],
            red[3] + red[7] + red[11] + red[15]);
    }
}

// One block. Threads [0,48): (ml,stat) pair sums its 32 block-partials,
// then thread 0 combines in fp64.
__global__ __launch_bounds__(64) void finalize(
        const float* __restrict__ partial, const float* __restrict__ t,
        float* __restrict__ out) {
    __shared__ float sums[48];
    int tid = threadIdx.x;
    if (tid < 48) {
        int ml   = tid >> 2;
        int stat = tid & 3;
        const float* p = partial + (size_t)ml * BPML * 4 + stat;
        float s = 0.0f;
        #pragma unroll
        for (int b = 0; b < BPML; ++b) s += p[b * 4];
        sums[tid] = s;
    }
    __syncthreads();
    if (tid == 0) {
        const double N = (double)NN;
        const double SIG2 = 0.01;   // SIGMA^2
        const double VKD  = 2.0;    // V_K * d
        double diss = 0.0, diffu = 0.0, dE = 0.0;
        for (int m = 0; m < MM; ++m) {
            double E0 = 0.0;
            for (int l = 0; l < LL; ++l) {
                int idx = m * LL + l;
                double sphi = (double)sums[idx * 4 + 0];
                double sd2  = (double)sums[idx * 4 + 1];
                double sdr  = (double)sums[idx * 4 + 2];
                double sv   = (double)sums[idx * 4 + 3];
                double E = 0.5 * sv / N + sphi / (N * N);
                if (l == 0) E0 = E;
                if (l == LL - 1) dE += E - E0;
                if (l < LL - 1) {
                    double dt = (double)t[l + 1] - (double)t[l];
                    diss  += sdr / N * dt;
                    diffu += SIG2 * (VKD + sd2 / (N * N)) * dt;
                }
            }
        }
        double res = (diss + diffu - 2.0 * dE) / (double)(MM * (LL - 1));
        out[0] = (float)(res * res);
    }
}

extern "C" void kernel_launch(void* const* d_in, const int* in_sizes, int n_in,
                              void* d_out, int out_size, void* d_ws, size_t ws_size,
                              hipStream_t stream) {
    const float* data = (const float*)d_in[0];
    const float* t    = (const float*)d_in[1];
    const float* w1   = (const float*)d_in[2];
    const float* b1   = (const float*)d_in[3];
    const float* W2   = (const float*)d_in[4];
    const float* b2   = (const float*)d_in[5];
    const float* w3   = (const float*)d_in[6];
    const float* b3   = (const float*)d_in[7];

    float4* coefg   = (float4*)d_ws;
    float4* partial = (float4*)((char*)d_ws + 8192);

    // 512 Hermite intervals, one wave each -> 128 blocks of 4 waves
    build_nodes<<<128, 256, 0, stream>>>(w1, b1, W2, b2, w3, b3, coefg);
    // 12 (m,l) * 32 blocks, 16 particles per block
    pair_kernel<<<NPBLK, 256, 0, stream>>>(data, coefg, partial);
    finalize<<<1, 64, 0, stream>>>((const float*)partial, t, (float*)d_out);
}